// Round 3
// baseline (1179.840 us; speedup 1.0000x reference)
//
#include <hip/hip_runtime.h>

// ---------------------------------------------------------------------------
// GCN 2-layer max-aggregation:
//   h1 = x @ w1.T + b1                        [N,32]
//   agg1 = max(segment_max(h1[src], dst), 0)  (relu + isolated-node fold)
//   h2 = agg1 @ w2.T + b2                     [N,32]
//   out = segment_max(h2[src], dst), -inf -> 0
//
// Float max via order-preserving u32 encoding + global_atomic_umax.
// ---------------------------------------------------------------------------

__device__ __forceinline__ unsigned encf(float f) {
    unsigned b = __float_as_uint(f);
    return b ^ (unsigned(int(b) >> 31) | 0x80000000u);
}
__device__ __forceinline__ float decf(unsigned u) {
    unsigned b = (u & 0x80000000u) ? (u ^ 0x80000000u) : ~u;
    return __uint_as_float(b);
}

#define ENC_ZERO   0x80000000u   // encf(0.0f)
#define ENC_NEGINF 0x007FFFFFu   // encf(-inf)

__global__ __launch_bounds__(256) void fill_u32_kernel(unsigned* __restrict__ p,
                                                       unsigned v, int n4) {
    int i = blockIdx.x * 256 + threadIdx.x;
    if (i < n4) reinterpret_cast<uint4*>(p)[i] = make_uint4(v, v, v, v);
}

// h1 = x @ w1.T + b1.  Block: 256 thr = 8 groups x 32 lanes; each group does
// 4 nodes (lane j = output channel j) -> 32 nodes/block.
__global__ __launch_bounds__(256) void linear1_kernel(
    const float* __restrict__ x, const float* __restrict__ w1,
    const float* __restrict__ b1, float* __restrict__ h1, int N)
{
    __shared__ float wsh[32][132];   // 32x128 padded
    __shared__ float xs[32][128];
    const int tid = threadIdx.x;
    for (int i = tid; i < 32 * 128; i += 256) wsh[i >> 7][i & 127] = w1[i];
    const int node0 = blockIdx.x * 32;
    const float4* x4 = reinterpret_cast<const float4*>(x + (size_t)node0 * 128);
    for (int q = tid; q < 32 * 32; q += 256) {         // 32 rows x 32 quads
        int row = q >> 5;
        if (node0 + row < N) {
            float4 v = x4[q];
            *reinterpret_cast<float4*>(&xs[row][(q & 31) * 4]) = v;
        }
    }
    __syncthreads();
    const int g = tid >> 5, j = tid & 31;
    const int nb = g * 4;
    const float bj = b1[j];
    float acc[4] = {bj, bj, bj, bj};
    const float4* wrow = reinterpret_cast<const float4*>(&wsh[j][0]);
    #pragma unroll 4
    for (int k4 = 0; k4 < 32; ++k4) {
        float4 w = wrow[k4];
        #pragma unroll
        for (int a = 0; a < 4; ++a) {
            float4 xv = *reinterpret_cast<const float4*>(&xs[nb + a][k4 * 4]);
            acc[a] += xv.x * w.x + xv.y * w.y + xv.z * w.z + xv.w * w.w;
        }
    }
    #pragma unroll
    for (int a = 0; a < 4; ++a) {
        int n = node0 + nb + a;
        if (n < N) h1[(size_t)n * 32 + j] = acc[a];
    }
}

// h2 = relu(agg1) @ w2.T + b2 ; relu already folded into the encoded max
// (accumulator was seeded with enc(0)).  Block: 8 groups x 32 lanes, 8
// nodes/group -> 64 nodes/block.
__global__ __launch_bounds__(256) void linear2_kernel(
    const unsigned* __restrict__ agg1, const float* __restrict__ w2,
    const float* __restrict__ b2, float* __restrict__ h2, int N)
{
    __shared__ float wsh[32][36];
    __shared__ float rs[64][32];
    const int tid = threadIdx.x;
    for (int i = tid; i < 32 * 32; i += 256) wsh[i >> 5][i & 31] = w2[i];
    const int node0 = blockIdx.x * 64;
    const uint4* a4 = reinterpret_cast<const uint4*>(agg1 + (size_t)node0 * 32);
    for (int q = tid; q < 64 * 8; q += 256) {          // 64 rows x 8 quads
        int row = q >> 3;
        if (node0 + row < N) {
            uint4 u = a4[q];
            float4 f = {decf(u.x), decf(u.y), decf(u.z), decf(u.w)};
            *reinterpret_cast<float4*>(&rs[row][(q & 7) * 4]) = f;
        }
    }
    __syncthreads();
    const int g = tid >> 5, j = tid & 31;
    const int nb = g * 8;
    const float bj = b2[j];
    float acc[8];
    #pragma unroll
    for (int a = 0; a < 8; ++a) acc[a] = bj;
    const float4* wrow = reinterpret_cast<const float4*>(&wsh[j][0]);
    #pragma unroll
    for (int k4 = 0; k4 < 8; ++k4) {
        float4 w = wrow[k4];
        #pragma unroll
        for (int a = 0; a < 8; ++a) {
            float4 xv = *reinterpret_cast<const float4*>(&rs[nb + a][k4 * 4]);
            acc[a] += xv.x * w.x + xv.y * w.y + xv.z * w.z + xv.w * w.w;
        }
    }
    #pragma unroll
    for (int a = 0; a < 8; ++a) {
        int n = node0 + nb + a;
        if (n < N) h2[(size_t)n * 32 + j] = acc[a];
    }
}

// Edge scatter: 8 threads/edge, each thread owns 4 channels (float4 gather,
// 4x fire-and-forget atomic umax).
__global__ __launch_bounds__(256) void scatter_max_kernel(
    const float* __restrict__ h, const int* __restrict__ src,
    const int* __restrict__ dst, unsigned* __restrict__ agg, int E)
{
    int t = blockIdx.x * 256 + threadIdx.x;
    int e = t >> 3;
    if (e >= E) return;
    int c = (t & 7) << 2;
    int s = src[e], d = dst[e];
    float4 v = *reinterpret_cast<const float4*>(h + (size_t)s * 32 + c);
    unsigned* a = agg + (size_t)d * 32 + c;
    atomicMax(a + 0, encf(v.x));
    atomicMax(a + 1, encf(v.y));
    atomicMax(a + 2, encf(v.z));
    atomicMax(a + 3, encf(v.w));
}

__global__ __launch_bounds__(256) void finalize_kernel(
    const unsigned* __restrict__ agg, float* __restrict__ out, int n)
{
    int i = blockIdx.x * 256 + threadIdx.x;
    if (i < n) {
        unsigned u = agg[i];
        out[i] = (u == ENC_NEGINF) ? 0.0f : decf(u);
    }
}

extern "C" void kernel_launch(void* const* d_in, const int* in_sizes, int n_in,
                              void* d_out, int out_size, void* d_ws, size_t ws_size,
                              hipStream_t stream)
{
    const float* x  = (const float*)d_in[0];
    const int*   ei = (const int*)d_in[1];
    const float* w1 = (const float*)d_in[2];
    const float* b1 = (const float*)d_in[3];
    const float* w2 = (const float*)d_in[4];
    const float* b2 = (const float*)d_in[5];
    float* out = (float*)d_out;

    const int N = in_sizes[0] / 128;
    const int E = in_sizes[1] / 2;
    const int C = (int)((size_t)N * 32);     // elems per [N,32] buffer

    // 3-buffer workspace layout (12.8 MB each @ N=100k):
    //   buf0: h1, later reused as agg2_enc
    //   buf1: agg1_enc
    //   buf2: h2
    float*    buf0 = (float*)d_ws;
    unsigned* buf1 = (unsigned*)((char*)d_ws + (size_t)C * 4);
    float*    buf2 = (float*)((char*)d_ws + (size_t)C * 8);

    const int n4 = C / 4;
    const int fillGrid = (n4 + 255) / 256;
    const int scatGrid = (int)(((long long)E * 8 + 255) / 256);

    // conv1: seed with enc(0) -> relu + isolated-node fold for free
    fill_u32_kernel<<<fillGrid, 256, 0, stream>>>(buf1, ENC_ZERO, n4);
    linear1_kernel<<<(N + 31) / 32, 256, 0, stream>>>(x, w1, b1, buf0, N);
    scatter_max_kernel<<<scatGrid, 256, 0, stream>>>(buf0, ei, ei + E, buf1, E);

    // conv2: seed with enc(-inf), decode sentinel -> 0 at the end
    fill_u32_kernel<<<fillGrid, 256, 0, stream>>>((unsigned*)buf0, ENC_NEGINF, n4);
    linear2_kernel<<<(N + 63) / 64, 256, 0, stream>>>(buf1, w2, b2, buf2, N);
    scatter_max_kernel<<<scatGrid, 256, 0, stream>>>(buf2, ei, ei + E, (unsigned*)buf0, E);

    finalize_kernel<<<(C + 255) / 256, 256, 0, stream>>>((unsigned*)buf0, out, C);
}

// Round 4
// 407.972 us; speedup vs baseline: 2.8920x; 2.8920x over previous
//
#include <hip/hip_runtime.h>
#include <math.h>

// ---------------------------------------------------------------------------
// GCN 2-layer max-aggregation via per-launch CSR (counting sort by dst):
//   offsets/csr_src built once, shared by both convs.
//   conv1: h1 = x@w1.T+b1 ; agg1[n] = max(0, max_{e:dst=n} h1[src_e])  (relu fold)
//   conv2: h2 = agg1@w2.T+b2 ; out[n] = deg==0 ? 0 : max_{e:dst=n} h2[src_e]
// No atomics in the aggregation; gather-max with one float4 store per node/8.
// ---------------------------------------------------------------------------

__global__ __launch_bounds__(256) void fill_s32_kernel(int* __restrict__ p, int v, int n) {
    int i = blockIdx.x * 256 + threadIdx.x;
    if (i < n) p[i] = v;
}

__global__ __launch_bounds__(256) void hist_kernel(const int* __restrict__ dst,
                                                   int* __restrict__ counts, int E) {
    int e = blockIdx.x * 256 + threadIdx.x;
    if (e < E) atomicAdd(&counts[dst[e]], 1);
}

// Per-256-block exclusive scan of counts -> offs (local), block totals -> partials.
__global__ __launch_bounds__(256) void scan_local_kernel(const int* __restrict__ counts,
                                                         int* __restrict__ offs,
                                                         int* __restrict__ partials, int N) {
    __shared__ int sh[256];
    int i = blockIdx.x * 256 + threadIdx.x;
    int v = (i < N) ? counts[i] : 0;
    sh[threadIdx.x] = v;
    __syncthreads();
    #pragma unroll
    for (int d = 1; d < 256; d <<= 1) {
        int t = (threadIdx.x >= d) ? sh[threadIdx.x - d] : 0;
        __syncthreads();
        sh[threadIdx.x] += t;
        __syncthreads();
    }
    if (i < N) offs[i] = sh[threadIdx.x] - v;           // exclusive
    if (threadIdx.x == 255) partials[blockIdx.x] = sh[255];
}

// Single block: exclusive scan of partials in place (chunks of 256 w/ carry).
__global__ __launch_bounds__(256) void scan_partials_kernel(int* __restrict__ partials, int nb) {
    __shared__ int sh[256];
    __shared__ int carry;
    if (threadIdx.x == 0) carry = 0;
    __syncthreads();
    for (int base = 0; base < nb; base += 256) {
        int i = base + threadIdx.x;
        int v = (i < nb) ? partials[i] : 0;
        sh[threadIdx.x] = v;
        __syncthreads();
        #pragma unroll
        for (int d = 1; d < 256; d <<= 1) {
            int t = (threadIdx.x >= d) ? sh[threadIdx.x - d] : 0;
            __syncthreads();
            sh[threadIdx.x] += t;
            __syncthreads();
        }
        if (i < nb) partials[i] = sh[threadIdx.x] - v + carry;
        __syncthreads();
        if (threadIdx.x == 0) carry += sh[255];
        __syncthreads();
    }
}

// offs[i] += block base; cursor[i] = offs[i]; offs[N] = E.
__global__ __launch_bounds__(256) void addback_kernel(int* __restrict__ offs,
                                                      int* __restrict__ cursor,
                                                      const int* __restrict__ partials,
                                                      int N, int E) {
    int i = blockIdx.x * 256 + threadIdx.x;
    if (i < N) {
        int v = offs[i] + partials[blockIdx.x];
        offs[i] = v;
        cursor[i] = v;
    } else if (i == N) {
        offs[N] = E;
    }
}

__global__ __launch_bounds__(256) void fill_csr_kernel(const int* __restrict__ src,
                                                       const int* __restrict__ dst,
                                                       int* __restrict__ cursor,
                                                       int* __restrict__ csr_src, int E) {
    int e = blockIdx.x * 256 + threadIdx.x;
    if (e < E) {
        int slot = atomicAdd(&cursor[dst[e]], 1);
        csr_src[slot] = src[e];
    }
}

// h1 = x @ w1.T + b1.  256 thr = 8 groups x 32 lanes; 4 nodes/group.
__global__ __launch_bounds__(256) void linear1_kernel(
    const float* __restrict__ x, const float* __restrict__ w1,
    const float* __restrict__ b1, float* __restrict__ h1, int N)
{
    __shared__ float wsh[32][132];
    __shared__ float xs[32][128];
    const int tid = threadIdx.x;
    for (int i = tid; i < 32 * 128; i += 256) wsh[i >> 7][i & 127] = w1[i];
    const int node0 = blockIdx.x * 32;
    const float4* x4 = reinterpret_cast<const float4*>(x + (size_t)node0 * 128);
    for (int q = tid; q < 32 * 32; q += 256) {
        int row = q >> 5;
        if (node0 + row < N) {
            float4 v = x4[q];
            *reinterpret_cast<float4*>(&xs[row][(q & 31) * 4]) = v;
        }
    }
    __syncthreads();
    const int g = tid >> 5, j = tid & 31;
    const int nb = g * 4;
    const float bj = b1[j];
    float acc[4] = {bj, bj, bj, bj};
    const float4* wrow = reinterpret_cast<const float4*>(&wsh[j][0]);
    #pragma unroll 4
    for (int k4 = 0; k4 < 32; ++k4) {
        float4 w = wrow[k4];
        #pragma unroll
        for (int a = 0; a < 4; ++a) {
            float4 xv = *reinterpret_cast<const float4*>(&xs[nb + a][k4 * 4]);
            acc[a] += xv.x * w.x + xv.y * w.y + xv.z * w.z + xv.w * w.w;
        }
    }
    #pragma unroll
    for (int a = 0; a < 4; ++a) {
        int n = node0 + nb + a;
        if (n < N) h1[(size_t)n * 32 + j] = acc[a];
    }
}

// h2 = agg1 @ w2.T + b2 (agg1 already >= 0; relu folded into conv1 seed).
__global__ __launch_bounds__(256) void linear2_kernel(
    const float* __restrict__ agg1, const float* __restrict__ w2,
    const float* __restrict__ b2, float* __restrict__ h2, int N)
{
    __shared__ float wsh[32][36];
    __shared__ float rs[64][32];
    const int tid = threadIdx.x;
    for (int i = tid; i < 32 * 32; i += 256) wsh[i >> 5][i & 31] = w2[i];
    const int node0 = blockIdx.x * 64;
    const float4* a4 = reinterpret_cast<const float4*>(agg1 + (size_t)node0 * 32);
    for (int q = tid; q < 64 * 8; q += 256) {
        int row = q >> 3;
        if (node0 + row < N) {
            float4 v = a4[q];
            *reinterpret_cast<float4*>(&rs[row][(q & 7) * 4]) = v;
        }
    }
    __syncthreads();
    const int g = tid >> 5, j = tid & 31;
    const int nb = g * 8;
    const float bj = b2[j];
    float acc[8];
    #pragma unroll
    for (int a = 0; a < 8; ++a) acc[a] = bj;
    const float4* wrow = reinterpret_cast<const float4*>(&wsh[j][0]);
    #pragma unroll
    for (int k4 = 0; k4 < 8; ++k4) {
        float4 w = wrow[k4];
        #pragma unroll
        for (int a = 0; a < 8; ++a) {
            float4 xv = *reinterpret_cast<const float4*>(&rs[nb + a][k4 * 4]);
            acc[a] += xv.x * w.x + xv.y * w.y + xv.z * w.z + xv.w * w.w;
        }
    }
    #pragma unroll
    for (int a = 0; a < 8; ++a) {
        int n = node0 + nb + a;
        if (n < N) h2[(size_t)n * 32 + j] = acc[a];
    }
}

// Gather-max over CSR: 8 threads/node, 4 channels each, 2-edge unroll.
// fixup: deg==0 -> 0 (conv2); conv1 uses seed=0 so deg==0 is already correct.
__global__ __launch_bounds__(256) void agg_max_kernel(
    const float* __restrict__ h, const int* __restrict__ offs,
    const int* __restrict__ csr_src, float* __restrict__ out,
    int N, float seed, int fixup)
{
    int t = blockIdx.x * 256 + threadIdx.x;
    int n = t >> 3;
    if (n >= N) return;
    int c = (t & 7) << 2;
    int k0 = offs[n], k1 = offs[n + 1];
    float4 acc = {seed, seed, seed, seed};
    int k = k0;
    for (; k + 1 < k1; k += 2) {
        int s0 = csr_src[k], s1 = csr_src[k + 1];
        float4 v0 = *reinterpret_cast<const float4*>(h + (size_t)s0 * 32 + c);
        float4 v1 = *reinterpret_cast<const float4*>(h + (size_t)s1 * 32 + c);
        acc.x = fmaxf(acc.x, fmaxf(v0.x, v1.x));
        acc.y = fmaxf(acc.y, fmaxf(v0.y, v1.y));
        acc.z = fmaxf(acc.z, fmaxf(v0.z, v1.z));
        acc.w = fmaxf(acc.w, fmaxf(v0.w, v1.w));
    }
    if (k < k1) {
        int s0 = csr_src[k];
        float4 v0 = *reinterpret_cast<const float4*>(h + (size_t)s0 * 32 + c);
        acc.x = fmaxf(acc.x, v0.x);
        acc.y = fmaxf(acc.y, v0.y);
        acc.z = fmaxf(acc.z, v0.z);
        acc.w = fmaxf(acc.w, v0.w);
    }
    if (fixup && k1 == k0) acc = make_float4(0.f, 0.f, 0.f, 0.f);
    *reinterpret_cast<float4*>(out + (size_t)n * 32 + c) = acc;
}

extern "C" void kernel_launch(void* const* d_in, const int* in_sizes, int n_in,
                              void* d_out, int out_size, void* d_ws, size_t ws_size,
                              hipStream_t stream)
{
    const float* x  = (const float*)d_in[0];
    const int*   ei = (const int*)d_in[1];
    const float* w1 = (const float*)d_in[2];
    const float* b1 = (const float*)d_in[3];
    const float* w2 = (const float*)d_in[4];
    const float* b2 = (const float*)d_in[5];
    float* out = (float*)d_out;

    const int N = in_sizes[0] / 128;
    const int E = in_sizes[1] / 2;
    const int C = (int)((size_t)N * 32);
    const int* src = ei;
    const int* dst = ei + E;

    // Workspace layout (~33 MB @ N=100k, E=1.6M):
    auto align256 = [](size_t v) { return (v + 255) & ~(size_t)255; };
    size_t off = 0;
    float* bufA = (float*)((char*)d_ws + off); off = align256(off + (size_t)C * 4);   // h1, then h2
    float* bufB = (float*)((char*)d_ws + off); off = align256(off + (size_t)C * 4);   // agg1
    int* offs    = (int*)((char*)d_ws + off); off = align256(off + (size_t)(N + 1) * 4);
    int* cursor  = (int*)((char*)d_ws + off); off = align256(off + (size_t)(N + 1) * 4); // also counts
    int* csr_src = (int*)((char*)d_ws + off); off = align256(off + (size_t)E * 4);
    int* partials = (int*)((char*)d_ws + off);
    int* counts = cursor;   // counts dead after scan_local; cursor written in addback

    const int nbScan = (N + 255) / 256;

    // --- CSR build (shared by both convs) ---
    fill_s32_kernel<<<(N + 255) / 256, 256, 0, stream>>>(counts, 0, N);
    hist_kernel<<<(E + 255) / 256, 256, 0, stream>>>(dst, counts, E);
    scan_local_kernel<<<nbScan, 256, 0, stream>>>(counts, offs, partials, N);
    scan_partials_kernel<<<1, 256, 0, stream>>>(partials, nbScan);
    addback_kernel<<<(N + 1 + 255) / 256, 256, 0, stream>>>(offs, cursor, partials, N, E);
    fill_csr_kernel<<<(E + 255) / 256, 256, 0, stream>>>(src, dst, cursor, csr_src, E);

    // --- conv1 ---
    linear1_kernel<<<(N + 31) / 32, 256, 0, stream>>>(x, w1, b1, bufA, N);
    agg_max_kernel<<<((N * 8) + 255) / 256, 256, 0, stream>>>(
        bufA, offs, csr_src, bufB, N, 0.0f, 0);          // seed 0 = relu + isolated fold

    // --- conv2 ---
    linear2_kernel<<<(N + 63) / 64, 256, 0, stream>>>(bufB, w2, b2, bufA, N);
    agg_max_kernel<<<((N * 8) + 255) / 256, 256, 0, stream>>>(
        bufA, offs, csr_src, out, N, -INFINITY, 1);      // deg==0 -> 0, writes d_out
}

// Round 6
// 361.625 us; speedup vs baseline: 3.2626x; 1.1282x over previous
//
#include <hip/hip_runtime.h>
#include <math.h>

// ---------------------------------------------------------------------------
// GCN 2-layer max-aggregation via per-launch CSR (counting sort by dst).
// CSR build is XCD-partitioned: dst-space is split into NR=8 ranges; block b
// serves range (b % 8), which the round-robin workgroup dispatcher places on
// XCD (b % 8). All atomics + csr_src stores for a range stay in ONE XCD's L2
// (no cross-XCD line thrash); the edge list is re-read once per range but is
// Infinity-Cache-resident. Correctness does NOT depend on the XCD mapping.
//   conv1: h1 = x@w1.T+b1 ; agg1[n] = max(0, max_{e:dst=n} h1[src_e]) (relu fold)
//   conv2: h2 = agg1@w2.T+b2 ; out[n] = deg==0 ? 0 : max_{e:dst=n} h2[src_e]
// ---------------------------------------------------------------------------

#define NR 8          // dst ranges == XCD count
#define NCHUNK 128    // edge-list chunks per range

__global__ __launch_bounds__(256) void fill_s32_kernel(int* __restrict__ p, int v, int n) {
    int i = blockIdx.x * 256 + threadIdx.x;
    if (i < n) p[i] = v;
}

// Histogram, XCD-partitioned: block b -> range (b&7), chunk (b>>3).
__global__ __launch_bounds__(256) void hist_part_kernel(
    const int* __restrict__ dst, int* __restrict__ counts, int N, int E)
{
    const int b = blockIdx.x;
    const int r = b & (NR - 1);
    const int c = b >> 3;
    const int rlo = (int)((long long)r * N / NR);
    const int rhi = (int)((long long)(r + 1) * N / NR);
    const int e0 = (int)((long long)c * E / NCHUNK);
    const int e1 = (int)((long long)(c + 1) * E / NCHUNK);
    for (int e = e0 + threadIdx.x; e < e1; e += 256) {
        int d = dst[e];
        if (d >= rlo && d < rhi) atomicAdd(&counts[d], 1);
    }
}

// Per-256-block exclusive scan of counts -> offs (local), block totals -> partials.
__global__ __launch_bounds__(256) void scan_local_kernel(const int* __restrict__ counts,
                                                         int* __restrict__ offs,
                                                         int* __restrict__ partials, int N) {
    __shared__ int sh[256];
    int i = blockIdx.x * 256 + threadIdx.x;
    int v = (i < N) ? counts[i] : 0;
    sh[threadIdx.x] = v;
    __syncthreads();
    #pragma unroll
    for (int d = 1; d < 256; d <<= 1) {
        int t = (threadIdx.x >= d) ? sh[threadIdx.x - d] : 0;
        __syncthreads();
        sh[threadIdx.x] += t;
        __syncthreads();
    }
    if (i < N) offs[i] = sh[threadIdx.x] - v;           // exclusive
    if (threadIdx.x == 255) partials[blockIdx.x] = sh[255];
}

// Single block: exclusive scan of partials in place (chunks of 256 w/ carry).
__global__ __launch_bounds__(256) void scan_partials_kernel(int* __restrict__ partials, int nb) {
    __shared__ int sh[256];
    __shared__ int carry;
    if (threadIdx.x == 0) carry = 0;
    __syncthreads();
    for (int base = 0; base < nb; base += 256) {
        int i = base + threadIdx.x;
        int v = (i < nb) ? partials[i] : 0;
        sh[threadIdx.x] = v;
        __syncthreads();
        #pragma unroll
        for (int d = 1; d < 256; d <<= 1) {
            int t = (threadIdx.x >= d) ? sh[threadIdx.x - d] : 0;
            __syncthreads();
            sh[threadIdx.x] += t;
            __syncthreads();
        }
        if (i < nb) partials[i] = sh[threadIdx.x] - v + carry;
        __syncthreads();
        if (threadIdx.x == 0) carry += sh[255];
        __syncthreads();
    }
}

// offs[i] += block base; cursor[i] = offs[i]; offs[N] = E.
__global__ __launch_bounds__(256) void addback_kernel(int* __restrict__ offs,
                                                      int* __restrict__ cursor,
                                                      const int* __restrict__ partials,
                                                      int N, int E) {
    int i = blockIdx.x * 256 + threadIdx.x;
    if (i < N) {
        int v = offs[i] + partials[blockIdx.x];
        offs[i] = v;
        cursor[i] = v;
    } else if (i == N) {
        offs[N] = E;
    }
}

// CSR fill, XCD-partitioned like hist_part: cursor atomics and csr_src stores
// for range r are issued only by blocks with blockIdx%8 == r.
__global__ __launch_bounds__(256) void fill_part_kernel(
    const int* __restrict__ src, const int* __restrict__ dst,
    int* __restrict__ cursor, int* __restrict__ csr_src, int N, int E)
{
    const int b = blockIdx.x;
    const int r = b & (NR - 1);
    const int c = b >> 3;
    const int rlo = (int)((long long)r * N / NR);
    const int rhi = (int)((long long)(r + 1) * N / NR);
    const int e0 = (int)((long long)c * E / NCHUNK);
    const int e1 = (int)((long long)(c + 1) * E / NCHUNK);
    for (int e = e0 + threadIdx.x; e < e1; e += 256) {
        int d = dst[e];
        if (d >= rlo && d < rhi) {
            int slot = atomicAdd(&cursor[d], 1);
            csr_src[slot] = src[e];
        }
    }
}

// h1 = x @ w1.T + b1.  256 thr = 8 groups x 32 lanes; 4 nodes/group.
__global__ __launch_bounds__(256) void linear1_kernel(
    const float* __restrict__ x, const float* __restrict__ w1,
    const float* __restrict__ b1, float* __restrict__ h1, int N)
{
    __shared__ float wsh[32][132];
    __shared__ float xs[32][128];
    const int tid = threadIdx.x;
    for (int i = tid; i < 32 * 128; i += 256) wsh[i >> 7][i & 127] = w1[i];
    const int node0 = blockIdx.x * 32;
    const float4* x4 = reinterpret_cast<const float4*>(x + (size_t)node0 * 128);
    for (int q = tid; q < 32 * 32; q += 256) {
        int row = q >> 5;
        if (node0 + row < N) {
            float4 v = x4[q];
            *reinterpret_cast<float4*>(&xs[row][(q & 31) * 4]) = v;
        }
    }
    __syncthreads();
    const int g = tid >> 5, j = tid & 31;
    const int nb = g * 4;
    const float bj = b1[j];
    float acc[4] = {bj, bj, bj, bj};
    const float4* wrow = reinterpret_cast<const float4*>(&wsh[j][0]);
    #pragma unroll 4
    for (int k4 = 0; k4 < 32; ++k4) {
        float4 w = wrow[k4];
        #pragma unroll
        for (int a = 0; a < 4; ++a) {
            float4 xv = *reinterpret_cast<const float4*>(&xs[nb + a][k4 * 4]);
            acc[a] += xv.x * w.x + xv.y * w.y + xv.z * w.z + xv.w * w.w;
        }
    }
    #pragma unroll
    for (int a = 0; a < 4; ++a) {
        int n = node0 + nb + a;
        if (n < N) h1[(size_t)n * 32 + j] = acc[a];
    }
}

// h2 = agg1 @ w2.T + b2 (agg1 already >= 0; relu folded into conv1 seed).
__global__ __launch_bounds__(256) void linear2_kernel(
    const float* __restrict__ agg1, const float* __restrict__ w2,
    const float* __restrict__ b2, float* __restrict__ h2, int N)
{
    __shared__ float wsh[32][36];
    __shared__ float rs[64][32];
    const int tid = threadIdx.x;
    for (int i = tid; i < 32 * 32; i += 256) wsh[i >> 5][i & 31] = w2[i];
    const int node0 = blockIdx.x * 64;
    const float4* a4 = reinterpret_cast<const float4*>(agg1 + (size_t)node0 * 32);
    for (int q = tid; q < 64 * 8; q += 256) {
        int row = q >> 3;
        if (node0 + row < N) {
            float4 v = a4[q];
            *reinterpret_cast<float4*>(&rs[row][(q & 7) * 4]) = v;
        }
    }
    __syncthreads();
    const int g = tid >> 5, j = tid & 31;
    const int nb = g * 8;
    const float bj = b2[j];
    float acc[8];
    #pragma unroll
    for (int a = 0; a < 8; ++a) acc[a] = bj;
    const float4* wrow = reinterpret_cast<const float4*>(&wsh[j][0]);
    #pragma unroll
    for (int k4 = 0; k4 < 8; ++k4) {
        float4 w = wrow[k4];
        #pragma unroll
        for (int a = 0; a < 8; ++a) {
            float4 xv = *reinterpret_cast<const float4*>(&rs[nb + a][k4 * 4]);
            acc[a] += xv.x * w.x + xv.y * w.y + xv.z * w.z + xv.w * w.w;
        }
    }
    #pragma unroll
    for (int a = 0; a < 8; ++a) {
        int n = node0 + nb + a;
        if (n < N) h2[(size_t)n * 32 + j] = acc[a];
    }
}

// Gather-max over CSR: 8 threads/node, 4 channels each, 2-edge unroll.
// fixup: deg==0 -> 0 (conv2); conv1 uses seed=0 so deg==0 is already correct.
__global__ __launch_bounds__(256) void agg_max_kernel(
    const float* __restrict__ h, const int* __restrict__ offs,
    const int* __restrict__ csr_src, float* __restrict__ out,
    int N, float seed, int fixup)
{
    int t = blockIdx.x * 256 + threadIdx.x;
    int n = t >> 3;
    if (n >= N) return;
    int c = (t & 7) << 2;
    int k0 = offs[n], k1 = offs[n + 1];
    float4 acc = {seed, seed, seed, seed};
    int k = k0;
    for (; k + 1 < k1; k += 2) {
        int s0 = csr_src[k], s1 = csr_src[k + 1];
        float4 v0 = *reinterpret_cast<const float4*>(h + (size_t)s0 * 32 + c);
        float4 v1 = *reinterpret_cast<const float4*>(h + (size_t)s1 * 32 + c);
        acc.x = fmaxf(acc.x, fmaxf(v0.x, v1.x));
        acc.y = fmaxf(acc.y, fmaxf(v0.y, v1.y));
        acc.z = fmaxf(acc.z, fmaxf(v0.z, v1.z));
        acc.w = fmaxf(acc.w, fmaxf(v0.w, v1.w));
    }
    if (k < k1) {
        int s0 = csr_src[k];
        float4 v0 = *reinterpret_cast<const float4*>(h + (size_t)s0 * 32 + c);
        acc.x = fmaxf(acc.x, v0.x);
        acc.y = fmaxf(acc.y, v0.y);
        acc.z = fmaxf(acc.z, v0.z);
        acc.w = fmaxf(acc.w, v0.w);
    }
    if (fixup && k1 == k0) acc = make_float4(0.f, 0.f, 0.f, 0.f);
    *reinterpret_cast<float4*>(out + (size_t)n * 32 + c) = acc;
}

extern "C" void kernel_launch(void* const* d_in, const int* in_sizes, int n_in,
                              void* d_out, int out_size, void* d_ws, size_t ws_size,
                              hipStream_t stream)
{
    const float* x  = (const float*)d_in[0];
    const int*   ei = (const int*)d_in[1];
    const float* w1 = (const float*)d_in[2];
    const float* b1 = (const float*)d_in[3];
    const float* w2 = (const float*)d_in[4];
    const float* b2 = (const float*)d_in[5];
    float* out = (float*)d_out;

    const int N = in_sizes[0] / 128;
    const int E = in_sizes[1] / 2;
    const int C = (int)((size_t)N * 32);
    const int* src = ei;
    const int* dst = ei + E;

    // Workspace layout (~33 MB @ N=100k, E=1.6M):
    auto align256 = [](size_t v) { return (v + 255) & ~(size_t)255; };
    size_t off = 0;
    float* bufA = (float*)((char*)d_ws + off); off = align256(off + (size_t)C * 4);   // h1, then h2
    float* bufB = (float*)((char*)d_ws + off); off = align256(off + (size_t)C * 4);   // agg1
    int* offs    = (int*)((char*)d_ws + off); off = align256(off + (size_t)(N + 1) * 4);
    int* cursor  = (int*)((char*)d_ws + off); off = align256(off + (size_t)(N + 1) * 4); // also counts
    int* csr_src = (int*)((char*)d_ws + off); off = align256(off + (size_t)E * 4);
    int* partials = (int*)((char*)d_ws + off);
    int* counts = cursor;   // counts dead after scan_local; cursor written in addback

    const int nbScan = (N + 255) / 256;

    // --- CSR build (shared by both convs), XCD-partitioned ---
    fill_s32_kernel<<<(N + 255) / 256, 256, 0, stream>>>(counts, 0, N);
    hist_part_kernel<<<NR * NCHUNK, 256, 0, stream>>>(dst, counts, N, E);
    scan_local_kernel<<<nbScan, 256, 0, stream>>>(counts, offs, partials, N);
    scan_partials_kernel<<<1, 256, 0, stream>>>(partials, nbScan);
    addback_kernel<<<(N + 1 + 255) / 256, 256, 0, stream>>>(offs, cursor, partials, N, E);
    fill_part_kernel<<<NR * NCHUNK, 256, 0, stream>>>(src, dst, cursor, csr_src, N, E);

    // --- conv1 ---
    linear1_kernel<<<(N + 31) / 32, 256, 0, stream>>>(x, w1, b1, bufA, N);
    agg_max_kernel<<<((N * 8) + 255) / 256, 256, 0, stream>>>(
        bufA, offs, csr_src, bufB, N, 0.0f, 0);          // seed 0 = relu + isolated fold

    // --- conv2 ---
    linear2_kernel<<<(N + 63) / 64, 256, 0, stream>>>(bufB, w2, b2, bufA, N);
    agg_max_kernel<<<((N * 8) + 255) / 256, 256, 0, stream>>>(
        bufA, offs, csr_src, out, N, -INFINITY, 1);      // deg==0 -> 0, writes d_out
}

// Round 7
// 288.632 us; speedup vs baseline: 4.0877x; 1.2529x over previous
//
#include <hip/hip_runtime.h>
#include <math.h>

// ---------------------------------------------------------------------------
// GCN 2-layer max-aggregation, ELL edge structure built with fully-coalesced
// global writes (two-level LDS bucketing). Structure shared by both convs:
//   A: bucket histogram (bucket = dst>>9, 512 nodes/bucket, B<=256)
//   B: exclusive scan of B bucket counts (1 block), init cursors/of_cnt
//   C: partition (src,dst) pairs into bucket regions; scatter only in LDS,
//      global writes are contiguous runs (~42 pairs avg)
//   D: per bucket, build 512xCAP ELL window + per-node counts in LDS,
//      stream out coalesced; deg>CAP edges -> overflow list (CAS-max fixup)
//   conv1: h1=x@w1.T+b1 ; agg1=max(0, max h1[src]) (relu+isolated fold, seed 0)
//   conv2: h2=agg1@w2.T+b2 ; out = deg==0 ? 0 : max h2[src]
// Assumes N <= 131072 (B <= 256). N=100k here.
// ---------------------------------------------------------------------------

#define NPB 512       // nodes per bucket
#define BSHIFT 9
#define CAP 32        // ELL slots per node (deg mean 16; overflow handled)
#define CCH 8192      // edges per partition-block chunk

__global__ __launch_bounds__(256) void fill_s32_kernel(int* __restrict__ p, int v, int n) {
    int i = blockIdx.x * 256 + threadIdx.x;
    if (i < n) p[i] = v;
}

// A: bucket histogram (LDS-local, one global atomic per bucket per block)
__global__ __launch_bounds__(256) void hist_buckets_kernel(
    const int* __restrict__ dst, int* __restrict__ bcnt, int B, int E)
{
    __shared__ int lc[256];
    const int tid = threadIdx.x;
    lc[tid] = 0;
    __syncthreads();
    for (int e = blockIdx.x * 256 + tid; e < E; e += gridDim.x * 256)
        atomicAdd(&lc[dst[e] >> BSHIFT], 1);
    __syncthreads();
    if (tid < B && lc[tid]) atomicAdd(&bcnt[tid], lc[tid]);
}

// B: exclusive scan of bcnt (reads bcnt==bcur, rewrites bcur=base). 1 block.
__global__ __launch_bounds__(256) void bucket_scan_kernel(
    int* __restrict__ bcur, int* __restrict__ bbase, int* __restrict__ of_cnt,
    int B, int E)
{
    __shared__ int sh[256];
    const int tid = threadIdx.x;
    int v = (tid < B) ? bcur[tid] : 0;
    sh[tid] = v;
    __syncthreads();
    #pragma unroll
    for (int d = 1; d < 256; d <<= 1) {
        int t = (tid >= d) ? sh[tid - d] : 0;
        __syncthreads();
        sh[tid] += t;
        __syncthreads();
    }
    if (tid < B) { int b = sh[tid] - v; bbase[tid] = b; bcur[tid] = b; }
    if (tid == 0) { bbase[B] = E; *of_cnt = 0; }
}

// C: partition pairs into bucket regions with coalesced writes.
__global__ __launch_bounds__(256) void partition_kernel(
    const int* __restrict__ src, const int* __restrict__ dst,
    int* __restrict__ bcur, uint2* __restrict__ pairs, int E)
{
    __shared__ uint2 stage[CCH];                       // 64 KB
    __shared__ int lcnt[256], loffs[256], lcur[256], gb[256], sh[256];
    const int tid = threadIdx.x;
    const int e0 = blockIdx.x * CCH;
    const int ecnt = min(CCH, E - e0);
    lcnt[tid] = 0;
    __syncthreads();
    for (int i = tid; i < ecnt; i += 256)
        atomicAdd(&lcnt[dst[e0 + i] >> BSHIFT], 1);
    __syncthreads();
    int v = lcnt[tid];
    sh[tid] = v;
    __syncthreads();
    #pragma unroll
    for (int d = 1; d < 256; d <<= 1) {
        int t = (tid >= d) ? sh[tid - d] : 0;
        __syncthreads();
        sh[tid] += t;
        __syncthreads();
    }
    loffs[tid] = sh[tid] - v;
    lcur[tid] = sh[tid] - v;
    gb[tid] = v ? atomicAdd(&bcur[tid], v) : 0;        // tid<B whenever v>0
    __syncthreads();
    for (int i = tid; i < ecnt; i += 256) {            // group by bucket in LDS
        int d = dst[e0 + i];
        int s = atomicAdd(&lcur[d >> BSHIFT], 1);
        stage[s] = make_uint2((unsigned)src[e0 + i], (unsigned)d);
    }
    __syncthreads();
    for (int i = tid; i < ecnt; i += 256) {            // contiguous runs out
        uint2 p = stage[i];
        int b = (int)(p.y >> BSHIFT);
        pairs[gb[b] + (i - loffs[b])] = p;
    }
}

// D: per-bucket ELL window in LDS, coalesced stream-out.
__global__ __launch_bounds__(256) void build_ell_kernel(
    const uint2* __restrict__ pairs, const int* __restrict__ bbase,
    int* __restrict__ ell, int* __restrict__ cnt,
    uint2* __restrict__ of_list, int* __restrict__ of_cnt, int N, int of_cap)
{
    __shared__ int lcnt[NPB];                          // 2 KB
    __shared__ int lell[NPB * CAP];                    // 64 KB
    const int tid = threadIdx.x, b = blockIdx.x;
    for (int i = tid; i < NPB; i += 256) lcnt[i] = 0;
    __syncthreads();
    const int p0 = bbase[b], p1 = bbase[b + 1];
    for (int i = p0 + tid; i < p1; i += 256) {
        uint2 p = pairs[i];
        int ln = (int)p.y - b * NPB;
        int s = atomicAdd(&lcnt[ln], 1);
        if (s < CAP) lell[ln * CAP + s] = (int)p.x;
        else { int oi = atomicAdd(of_cnt, 1); if (oi < of_cap) of_list[oi] = p; }
    }
    __syncthreads();
    const size_t eb = (size_t)b * NPB * CAP;
    for (int i = tid; i < NPB * CAP; i += 256) ell[eb + i] = lell[i];
    const int n0 = b * NPB;
    for (int i = tid; i < NPB; i += 256)
        if (n0 + i < N) cnt[n0 + i] = lcnt[i];
}

// h1 = x @ w1.T + b1.  256 thr = 8 groups x 32 lanes; 4 nodes/group.
__global__ __launch_bounds__(256) void linear1_kernel(
    const float* __restrict__ x, const float* __restrict__ w1,
    const float* __restrict__ b1, float* __restrict__ h1, int N)
{
    __shared__ float wsh[32][132];
    __shared__ float xs[32][128];
    const int tid = threadIdx.x;
    for (int i = tid; i < 32 * 128; i += 256) wsh[i >> 7][i & 127] = w1[i];
    const int node0 = blockIdx.x * 32;
    const float4* x4 = reinterpret_cast<const float4*>(x + (size_t)node0 * 128);
    for (int q = tid; q < 32 * 32; q += 256) {
        int row = q >> 5;
        if (node0 + row < N) {
            float4 v = x4[q];
            *reinterpret_cast<float4*>(&xs[row][(q & 31) * 4]) = v;
        }
    }
    __syncthreads();
    const int g = tid >> 5, j = tid & 31;
    const int nb = g * 4;
    const float bj = b1[j];
    float acc[4] = {bj, bj, bj, bj};
    const float4* wrow = reinterpret_cast<const float4*>(&wsh[j][0]);
    #pragma unroll 4
    for (int k4 = 0; k4 < 32; ++k4) {
        float4 w = wrow[k4];
        #pragma unroll
        for (int a = 0; a < 4; ++a) {
            float4 xv = *reinterpret_cast<const float4*>(&xs[nb + a][k4 * 4]);
            acc[a] += xv.x * w.x + xv.y * w.y + xv.z * w.z + xv.w * w.w;
        }
    }
    #pragma unroll
    for (int a = 0; a < 4; ++a) {
        int n = node0 + nb + a;
        if (n < N) h1[(size_t)n * 32 + j] = acc[a];
    }
}

// h2 = agg1 @ w2.T + b2.
__global__ __launch_bounds__(256) void linear2_kernel(
    const float* __restrict__ agg1, const float* __restrict__ w2,
    const float* __restrict__ b2, float* __restrict__ h2, int N)
{
    __shared__ float wsh[32][36];
    __shared__ float rs[64][32];
    const int tid = threadIdx.x;
    for (int i = tid; i < 32 * 32; i += 256) wsh[i >> 5][i & 31] = w2[i];
    const int node0 = blockIdx.x * 64;
    const float4* a4 = reinterpret_cast<const float4*>(agg1 + (size_t)node0 * 32);
    for (int q = tid; q < 64 * 8; q += 256) {
        int row = q >> 3;
        if (node0 + row < N) {
            float4 v = a4[q];
            *reinterpret_cast<float4*>(&rs[row][(q & 7) * 4]) = v;
        }
    }
    __syncthreads();
    const int g = tid >> 5, j = tid & 31;
    const int nb = g * 8;
    const float bj = b2[j];
    float acc[8];
    #pragma unroll
    for (int a = 0; a < 8; ++a) acc[a] = bj;
    const float4* wrow = reinterpret_cast<const float4*>(&wsh[j][0]);
    #pragma unroll
    for (int k4 = 0; k4 < 8; ++k4) {
        float4 w = wrow[k4];
        #pragma unroll
        for (int a = 0; a < 8; ++a) {
            float4 xv = *reinterpret_cast<const float4*>(&rs[nb + a][k4 * 4]);
            acc[a] += xv.x * w.x + xv.y * w.y + xv.z * w.z + xv.w * w.w;
        }
    }
    #pragma unroll
    for (int a = 0; a < 8; ++a) {
        int n = node0 + nb + a;
        if (n < N) h2[(size_t)n * 32 + j] = acc[a];
    }
}

// Gather-max over ELL rows: 8 threads/node, 4 channels each.
__global__ __launch_bounds__(256) void agg_ell_kernel(
    const float* __restrict__ h, const int* __restrict__ cnt,
    const int* __restrict__ ell, float* __restrict__ out,
    int N, float seed, int fixup)
{
    int t = blockIdx.x * 256 + threadIdx.x;
    int n = t >> 3;
    if (n >= N) return;
    int c = (t & 7) << 2;
    int total = cnt[n];
    int deg = min(total, CAP);
    const int* row = ell + (size_t)n * CAP;
    float4 acc = {seed, seed, seed, seed};
    int k = 0;
    for (; k + 1 < deg; k += 2) {
        int s0 = row[k], s1 = row[k + 1];
        float4 v0 = *reinterpret_cast<const float4*>(h + (size_t)s0 * 32 + c);
        float4 v1 = *reinterpret_cast<const float4*>(h + (size_t)s1 * 32 + c);
        acc.x = fmaxf(acc.x, fmaxf(v0.x, v1.x));
        acc.y = fmaxf(acc.y, fmaxf(v0.y, v1.y));
        acc.z = fmaxf(acc.z, fmaxf(v0.z, v1.z));
        acc.w = fmaxf(acc.w, fmaxf(v0.w, v1.w));
    }
    if (k < deg) {
        int s0 = row[k];
        float4 v0 = *reinterpret_cast<const float4*>(h + (size_t)s0 * 32 + c);
        acc.x = fmaxf(acc.x, v0.x);
        acc.y = fmaxf(acc.y, v0.y);
        acc.z = fmaxf(acc.z, v0.z);
        acc.w = fmaxf(acc.w, v0.w);
    }
    if (fixup && total == 0) acc = make_float4(0.f, 0.f, 0.f, 0.f);
    *reinterpret_cast<float4*>(out + (size_t)n * 32 + c) = acc;
}

__device__ __forceinline__ void atomicMaxF(float* a, float v) {
    int* ai = (int*)a;
    int old = *ai;
    while (v > __int_as_float(old)) {
        int assumed = old;
        old = atomicCAS(ai, assumed, __float_as_int(v));
        if (old == assumed) break;
    }
}

// Overflow edges (deg>CAP; ~0-20 in practice): CAS float-max fixup.
__global__ __launch_bounds__(256) void overflow_fixup_kernel(
    const float* __restrict__ h, const uint2* __restrict__ of_list,
    const int* __restrict__ of_cnt, float* __restrict__ out, int of_cap)
{
    int m = min(*of_cnt, of_cap);
    for (int t = blockIdx.x * 256 + threadIdx.x; t < m * 8; t += gridDim.x * 256) {
        int e = t >> 3, c = (t & 7) << 2;
        uint2 p = of_list[e];
        const float* hv = h + (size_t)p.x * 32 + c;
        float* a = out + (size_t)p.y * 32 + c;
        atomicMaxF(a + 0, hv[0]);
        atomicMaxF(a + 1, hv[1]);
        atomicMaxF(a + 2, hv[2]);
        atomicMaxF(a + 3, hv[3]);
    }
}

extern "C" void kernel_launch(void* const* d_in, const int* in_sizes, int n_in,
                              void* d_out, int out_size, void* d_ws, size_t ws_size,
                              hipStream_t stream)
{
    const float* x  = (const float*)d_in[0];
    const int*   ei = (const int*)d_in[1];
    const float* w1 = (const float*)d_in[2];
    const float* b1 = (const float*)d_in[3];
    const float* w2 = (const float*)d_in[4];
    const float* b2 = (const float*)d_in[5];
    float* out = (float*)d_out;

    const int N = in_sizes[0] / 128;
    const int E = in_sizes[1] / 2;
    const int C = (int)((size_t)N * 32);
    const int B = (N + NPB - 1) / NPB;          // <=256 for N<=131072
    const int* src = ei;
    const int* dst = ei + E;

    auto align256 = [](size_t v) { return (v + 255) & ~(size_t)255; };
    size_t off = 0;
    // Region R: pairs (E*8 B) until build_ell, then bufA = h1/h2 (C*4 B).
    size_t rsize = (size_t)C * 4 > (size_t)E * 8 ? (size_t)C * 4 : (size_t)E * 8;
    char* base = (char*)d_ws;
    uint2* pairs = (uint2*)(base + off);
    float* bufA  = (float*)(base + off);       off = align256(off + rsize);
    float* bufB  = (float*)(base + off);       off = align256(off + (size_t)C * 4);    // agg1
    int*   ell   = (int*)(base + off);         off = align256(off + (size_t)B * NPB * CAP * 4);
    int*   cnt   = (int*)(base + off);         off = align256(off + (size_t)N * 4);
    int*   bbase = (int*)(base + off);         off = align256(off + (size_t)(B + 1) * 4);
    int*   bcur  = (int*)(base + off);         off = align256(off + (size_t)B * 4);
    int*   of_cnt = (int*)(base + off);        off = align256(off + 256);
    uint2* of_list = (uint2*)(base + off);
    size_t rem = (ws_size > off) ? (ws_size - off) / 8 : 0;
    int of_cap = (int)((rem < (size_t)E) ? rem : (size_t)E);

    // --- shared edge structure ---
    fill_s32_kernel<<<(B + 255) / 256, 256, 0, stream>>>(bcur, 0, B);
    hist_buckets_kernel<<<256, 256, 0, stream>>>(dst, bcur, B, E);
    bucket_scan_kernel<<<1, 256, 0, stream>>>(bcur, bbase, of_cnt, B, E);
    partition_kernel<<<(E + CCH - 1) / CCH, 256, 0, stream>>>(src, dst, bcur, pairs, E);
    build_ell_kernel<<<B, 256, 0, stream>>>(pairs, bbase, ell, cnt, of_list, of_cnt, N, of_cap);

    const int aggGrid = (int)(((size_t)N * 8 + 255) / 256);

    // --- conv1 (seed 0 folds relu + isolated-node fix) ---
    linear1_kernel<<<(N + 31) / 32, 256, 0, stream>>>(x, w1, b1, bufA, N);
    agg_ell_kernel<<<aggGrid, 256, 0, stream>>>(bufA, cnt, ell, bufB, N, 0.0f, 0);
    overflow_fixup_kernel<<<32, 256, 0, stream>>>(bufA, of_list, of_cnt, bufB, of_cap);

    // --- conv2 ---
    linear2_kernel<<<(N + 63) / 64, 256, 0, stream>>>(bufB, w2, b2, bufA, N);
    agg_ell_kernel<<<aggGrid, 256, 0, stream>>>(bufA, cnt, ell, out, N, -INFINITY, 1);
    overflow_fixup_kernel<<<32, 256, 0, stream>>>(bufA, of_list, of_cnt, out, of_cap);
}

// Round 10
// 271.581 us; speedup vs baseline: 4.3443x; 1.0628x over previous
//
#include <hip/hip_runtime.h>
#include <math.h>

// ---------------------------------------------------------------------------
// GCN 2-layer max-aggregation, ELL edge structure built with fully-coalesced
// global writes (two-level LDS bucketing). Structure shared by both convs.
//   linear1: split-bf16 MFMA (x=xh+xl, w=wh+wl; 3 mfma terms ~ f32 accuracy)
//   conv1: agg1 = max(0, max h1[src])  (relu + isolated fold via seed 0)
//   conv2: h2 = agg1@w2.T+b2 ; out = deg==0 ? 0 : max h2[src]
// Assumes N <= 131072 (B <= 256). N=100k here.
// ---------------------------------------------------------------------------

#define NPB 512       // nodes per bucket
#define BSHIFT 9
#define CAP 32        // ELL slots per node
#define CCH 2048      // edges per partition-block chunk (16KB stage, ~7 blk/CU)
#define BPAD 16       // bcur padding: one counter per 64B line

typedef __attribute__((ext_vector_type(8))) short bf16x8;
typedef __attribute__((ext_vector_type(4))) float f32x4;

__global__ __launch_bounds__(256) void fill_s32_kernel(int* __restrict__ p, int v, int n) {
    int i = blockIdx.x * 256 + threadIdx.x;
    if (i < n) p[i] = v;
}

// A: bucket histogram (LDS-local, one global atomic per bucket per block)
__global__ __launch_bounds__(256) void hist_buckets_kernel(
    const int* __restrict__ dst, int* __restrict__ bcnt, int B, int E)
{
    __shared__ int lc[256];
    const int tid = threadIdx.x;
    lc[tid] = 0;
    __syncthreads();
    for (int e = blockIdx.x * 256 + tid; e < E; e += gridDim.x * 256)
        atomicAdd(&lc[dst[e] >> BSHIFT], 1);
    __syncthreads();
    if (tid < B && lc[tid]) atomicAdd(&bcnt[tid * BPAD], lc[tid]);
}

// B: exclusive scan of bcnt (reads padded bcur, rewrites bcur=base). 1 block.
__global__ __launch_bounds__(256) void bucket_scan_kernel(
    int* __restrict__ bcur, int* __restrict__ bbase, int* __restrict__ of_cnt,
    int B, int E)
{
    __shared__ int sh[256];
    const int tid = threadIdx.x;
    int v = (tid < B) ? bcur[tid * BPAD] : 0;
    sh[tid] = v;
    __syncthreads();
    #pragma unroll
    for (int d = 1; d < 256; d <<= 1) {
        int t = (tid >= d) ? sh[tid - d] : 0;
        __syncthreads();
        sh[tid] += t;
        __syncthreads();
    }
    if (tid < B) { int b = sh[tid] - v; bbase[tid] = b; bcur[tid * BPAD] = b; }
    if (tid == 0) { bbase[B] = E; *of_cnt = 0; }
}

// C: partition pairs into bucket regions with coalesced writes.
__global__ __launch_bounds__(256) void partition_kernel(
    const int* __restrict__ src, const int* __restrict__ dst,
    int* __restrict__ bcur, uint2* __restrict__ pairs, int E)
{
    __shared__ uint2 stage[CCH];                       // 16 KB
    __shared__ int lcnt[256], loffs[256], lcur[256], gb[256], sh[256];
    const int tid = threadIdx.x;
    const int e0 = blockIdx.x * CCH;
    const int ecnt = min(CCH, E - e0);
    lcnt[tid] = 0;
    __syncthreads();
    for (int i = tid; i < ecnt; i += 256)
        atomicAdd(&lcnt[dst[e0 + i] >> BSHIFT], 1);
    __syncthreads();
    int v = lcnt[tid];
    sh[tid] = v;
    __syncthreads();
    #pragma unroll
    for (int d = 1; d < 256; d <<= 1) {
        int t = (tid >= d) ? sh[tid - d] : 0;
        __syncthreads();
        sh[tid] += t;
        __syncthreads();
    }
    loffs[tid] = sh[tid] - v;
    lcur[tid] = sh[tid] - v;
    gb[tid] = v ? atomicAdd(&bcur[tid * BPAD], v) : 0; // tid<B whenever v>0
    __syncthreads();
    for (int i = tid; i < ecnt; i += 256) {            // group by bucket in LDS
        int d = dst[e0 + i];
        int s = atomicAdd(&lcur[d >> BSHIFT], 1);
        stage[s] = make_uint2((unsigned)src[e0 + i], (unsigned)d);
    }
    __syncthreads();
    for (int i = tid; i < ecnt; i += 256) {            // contiguous runs out
        uint2 p = stage[i];
        int b = (int)(p.y >> BSHIFT);
        pairs[gb[b] + (i - loffs[b])] = p;
    }
}

// D: per-bucket ELL window in LDS, coalesced stream-out.
__global__ __launch_bounds__(256) void build_ell_kernel(
    const uint2* __restrict__ pairs, const int* __restrict__ bbase,
    int* __restrict__ ell, int* __restrict__ cnt,
    uint2* __restrict__ of_list, int* __restrict__ of_cnt, int N, int of_cap)
{
    __shared__ int lcnt[NPB];                          // 2 KB
    __shared__ int lell[NPB * CAP];                    // 64 KB
    const int tid = threadIdx.x, b = blockIdx.x;
    for (int i = tid; i < NPB; i += 256) lcnt[i] = 0;
    __syncthreads();
    const int p0 = bbase[b], p1 = bbase[b + 1];
    for (int i = p0 + tid; i < p1; i += 256) {
        uint2 p = pairs[i];
        int ln = (int)p.y - b * NPB;
        int s = atomicAdd(&lcnt[ln], 1);
        if (s < CAP) lell[ln * CAP + s] = (int)p.x;
        else { int oi = atomicAdd(of_cnt, 1); if (oi < of_cap) of_list[oi] = p; }
    }
    __syncthreads();
    const size_t eb = (size_t)b * NPB * CAP;
    for (int i = tid; i < NPB * CAP; i += 256) ell[eb + i] = lell[i];
    const int n0 = b * NPB;
    for (int i = tid; i < NPB; i += 256)
        if (n0 + i < N) cnt[n0 + i] = lcnt[i];
}

// Split f32 -> bf16 hi + bf16 lo (truncate; residual exact by Sterbenz).
__device__ __forceinline__ void split_bf16(float f, unsigned short& hi, unsigned short& lo) {
    unsigned u = __float_as_uint(f);
    hi = (unsigned short)(u >> 16);
    float fh = __uint_as_float(u & 0xffff0000u);
    float r = f - fh;
    lo = (unsigned short)(__float_as_uint(r) >> 16);
}

// h1 = x @ w1.T + b1 via split-bf16 MFMA.
// Block = 256 thr = 4 waves; wave w does nodes [node0+16w, +16), all 32 ch.
// Fragments (16x16x32 bf16): A row=lane&15, k=(lane>>4)*8+j; B col=lane&15,
// same k; D col=lane&15, row=(lane>>4)*4+reg  [HW-verified mapping].
#define L1S 136   // LDS row stride in shorts (128 + 8 pad), 272B, 16B-aligned
__global__ __launch_bounds__(256) void linear1_mfma_kernel(
    const float* __restrict__ x, const float* __restrict__ w1,
    const float* __restrict__ b1, float* __restrict__ h1, int N)
{
    __shared__ unsigned short xh[64 * L1S];
    __shared__ unsigned short xl[64 * L1S];
    __shared__ unsigned short wh[32 * L1S];
    __shared__ unsigned short wl[32 * L1S];
    const int tid = threadIdx.x;
    const int node0 = blockIdx.x * 64;
    // stage w1 [32][128]
    for (int q = tid; q < 32 * 32; q += 256) {
        int row = q >> 5, qc = (q & 31) * 4;
        float4 v = *reinterpret_cast<const float4*>(w1 + row * 128 + qc);
        unsigned short h0, l0, h1s, l1s, h2, l2, h3, l3;
        split_bf16(v.x, h0, l0); split_bf16(v.y, h1s, l1s);
        split_bf16(v.z, h2, l2); split_bf16(v.w, h3, l3);
        short4 hv = {(short)h0, (short)h1s, (short)h2, (short)h3};
        short4 lv = {(short)l0, (short)l1s, (short)l2, (short)l3};
        *reinterpret_cast<short4*>(&wh[row * L1S + qc]) = hv;
        *reinterpret_cast<short4*>(&wl[row * L1S + qc]) = lv;
    }
    // stage x [64][128]
    for (int q = tid; q < 64 * 32; q += 256) {
        int row = q >> 5, qc = (q & 31) * 4;
        if (node0 + row < N) {
            float4 v = *reinterpret_cast<const float4*>(x + (size_t)(node0 + row) * 128 + qc);
            unsigned short h0, l0, h1s, l1s, h2, l2, h3, l3;
            split_bf16(v.x, h0, l0); split_bf16(v.y, h1s, l1s);
            split_bf16(v.z, h2, l2); split_bf16(v.w, h3, l3);
            short4 hv = {(short)h0, (short)h1s, (short)h2, (short)h3};
            short4 lv = {(short)l0, (short)l1s, (short)l2, (short)l3};
            *reinterpret_cast<short4*>(&xh[row * L1S + qc]) = hv;
            *reinterpret_cast<short4*>(&xl[row * L1S + qc]) = lv;
        }
    }
    __syncthreads();
    const int wid = tid >> 6, lane = tid & 63;
    const int arow = wid * 16 + (lane & 15);
    const int koff = (lane >> 4) * 8;
    bf16x8 ah[4], al[4], bh[2][4], bl[2][4];
    #pragma unroll
    for (int kt = 0; kt < 4; ++kt) {
        ah[kt] = *reinterpret_cast<const bf16x8*>(&xh[arow * L1S + kt * 32 + koff]);
        al[kt] = *reinterpret_cast<const bf16x8*>(&xl[arow * L1S + kt * 32 + koff]);
    }
    #pragma unroll
    for (int nt = 0; nt < 2; ++nt) {
        int ch = nt * 16 + (lane & 15);
        #pragma unroll
        for (int kt = 0; kt < 4; ++kt) {
            bh[nt][kt] = *reinterpret_cast<const bf16x8*>(&wh[ch * L1S + kt * 32 + koff]);
            bl[nt][kt] = *reinterpret_cast<const bf16x8*>(&wl[ch * L1S + kt * 32 + koff]);
        }
    }
    f32x4 acc[2] = {{0.f, 0.f, 0.f, 0.f}, {0.f, 0.f, 0.f, 0.f}};
    #pragma unroll
    for (int nt = 0; nt < 2; ++nt)
        #pragma unroll
        for (int kt = 0; kt < 4; ++kt) {
            acc[nt] = __builtin_amdgcn_mfma_f32_16x16x32_bf16(ah[kt], bh[nt][kt], acc[nt], 0, 0, 0);
            acc[nt] = __builtin_amdgcn_mfma_f32_16x16x32_bf16(ah[kt], bl[nt][kt], acc[nt], 0, 0, 0);
            acc[nt] = __builtin_amdgcn_mfma_f32_16x16x32_bf16(al[kt], bh[nt][kt], acc[nt], 0, 0, 0);
        }
    const int col = lane & 15, r0 = (lane >> 4) * 4;
    #pragma unroll
    for (int nt = 0; nt < 2; ++nt) {
        int ch = nt * 16 + col;
        float bias = b1[ch];
        #pragma unroll
        for (int r = 0; r < 4; ++r) {
            int n = node0 + wid * 16 + r0 + r;
            if (n < N) h1[(size_t)n * 32 + ch] = acc[nt][r] + bias;
        }
    }
}

// h2 = agg1 @ w2.T + b2 (vector; K=32, cheap).
__global__ __launch_bounds__(256) void linear2_kernel(
    const float* __restrict__ agg1, const float* __restrict__ w2,
    const float* __restrict__ b2, float* __restrict__ h2, int N)
{
    __shared__ float wsh[32][36];
    __shared__ float rs[64][32];
    const int tid = threadIdx.x;
    for (int i = tid; i < 32 * 32; i += 256) wsh[i >> 5][i & 31] = w2[i];
    const int node0 = blockIdx.x * 64;
    const float4* a4 = reinterpret_cast<const float4*>(agg1 + (size_t)node0 * 32);
    for (int q = tid; q < 64 * 8; q += 256) {
        int row = q >> 3;
        if (node0 + row < N) {
            float4 v = a4[q];
            *reinterpret_cast<float4*>(&rs[row][(q & 7) * 4]) = v;
        }
    }
    __syncthreads();
    const int g = tid >> 5, j = tid & 31;
    const int nb = g * 8;
    const float bj = b2[j];
    float acc[8];
    #pragma unroll
    for (int a = 0; a < 8; ++a) acc[a] = bj;
    const float4* wrow = reinterpret_cast<const float4*>(&wsh[j][0]);
    #pragma unroll
    for (int k4 = 0; k4 < 8; ++k4) {
        float4 w = wrow[k4];
        #pragma unroll
        for (int a = 0; a < 8; ++a) {
            float4 xv = *reinterpret_cast<const float4*>(&rs[nb + a][k4 * 4]);
            acc[a] += xv.x * w.x + xv.y * w.y + xv.z * w.z + xv.w * w.w;
        }
    }
    #pragma unroll
    for (int a = 0; a < 8; ++a) {
        int n = node0 + nb + a;
        if (n < N) h2[(size_t)n * 32 + j] = acc[a];
    }
}

// Gather-max over ELL rows: 8 threads/node, 4 channels each.
__global__ __launch_bounds__(256) void agg_ell_kernel(
    const float* __restrict__ h, const int* __restrict__ cnt,
    const int* __restrict__ ell, float* __restrict__ out,
    int N, float seed, int fixup)
{
    int t = blockIdx.x * 256 + threadIdx.x;
    int n = t >> 3;
    if (n >= N) return;
    int c = (t & 7) << 2;
    int total = cnt[n];
    int deg = min(total, CAP);
    const int* row = ell + (size_t)n * CAP;
    float4 acc = {seed, seed, seed, seed};
    int k = 0;
    for (; k + 1 < deg; k += 2) {
        int s0 = row[k], s1 = row[k + 1];
        float4 v0 = *reinterpret_cast<const float4*>(h + (size_t)s0 * 32 + c);
        float4 v1 = *reinterpret_cast<const float4*>(h + (size_t)s1 * 32 + c);
        acc.x = fmaxf(acc.x, fmaxf(v0.x, v1.x));
        acc.y = fmaxf(acc.y, fmaxf(v0.y, v1.y));
        acc.z = fmaxf(acc.z, fmaxf(v0.z, v1.z));
        acc.w = fmaxf(acc.w, fmaxf(v0.w, v1.w));
    }
    if (k < deg) {
        int s0 = row[k];
        float4 v0 = *reinterpret_cast<const float4*>(h + (size_t)s0 * 32 + c);
        acc.x = fmaxf(acc.x, v0.x);
        acc.y = fmaxf(acc.y, v0.y);
        acc.z = fmaxf(acc.z, v0.z);
        acc.w = fmaxf(acc.w, v0.w);
    }
    if (fixup && total == 0) acc = make_float4(0.f, 0.f, 0.f, 0.f);
    *reinterpret_cast<float4*>(out + (size_t)n * 32 + c) = acc;
}

__device__ __forceinline__ void atomicMaxF(float* a, float v) {
    int* ai = (int*)a;
    int old = *ai;
    while (v > __int_as_float(old)) {
        int assumed = old;
        old = atomicCAS(ai, assumed, __float_as_int(v));
        if (old == assumed) break;
    }
}

// Overflow edges (deg>CAP; ~0-20 in practice): CAS float-max fixup.
__global__ __launch_bounds__(256) void overflow_fixup_kernel(
    const float* __restrict__ h, const uint2* __restrict__ of_list,
    const int* __restrict__ of_cnt, float* __restrict__ out, int of_cap)
{
    int m = min(*of_cnt, of_cap);
    for (int t = blockIdx.x * 256 + threadIdx.x; t < m * 8; t += gridDim.x * 256) {
        int e = t >> 3, c = (t & 7) << 2;
        uint2 p = of_list[e];
        const float* hv = h + (size_t)p.x * 32 + c;
        float* a = out + (size_t)p.y * 32 + c;
        atomicMaxF(a + 0, hv[0]);
        atomicMaxF(a + 1, hv[1]);
        atomicMaxF(a + 2, hv[2]);
        atomicMaxF(a + 3, hv[3]);
    }
}

extern "C" void kernel_launch(void* const* d_in, const int* in_sizes, int n_in,
                              void* d_out, int out_size, void* d_ws, size_t ws_size,
                              hipStream_t stream)
{
    const float* x  = (const float*)d_in[0];
    const int*   ei = (const int*)d_in[1];
    const float* w1 = (const float*)d_in[2];
    const float* b1 = (const float*)d_in[3];
    const float* w2 = (const float*)d_in[4];
    const float* b2 = (const float*)d_in[5];
    float* out = (float*)d_out;

    const int N = in_sizes[0] / 128;
    const int E = in_sizes[1] / 2;
    const int C = (int)((size_t)N * 32);
    const int B = (N + NPB - 1) / NPB;          // <=256 for N<=131072
    const int* src = ei;
    const int* dst = ei + E;

    auto align256 = [](size_t v) { return (v + 255) & ~(size_t)255; };
    size_t off = 0;
    // Region R: pairs (E*8 B) until build_ell, then bufA = h1/h2 (C*4 B).
    size_t rsize = (size_t)C * 4 > (size_t)E * 8 ? (size_t)C * 4 : (size_t)E * 8;
    char* base = (char*)d_ws;
    uint2* pairs = (uint2*)(base + off);
    float* bufA  = (float*)(base + off);       off = align256(off + rsize);
    float* bufB  = (float*)(base + off);       off = align256(off + (size_t)C * 4);    // agg1
    int*   ell   = (int*)(base + off);         off = align256(off + (size_t)B * NPB * CAP * 4);
    int*   cnt   = (int*)(base + off);         off = align256(off + (size_t)N * 4);
    int*   bbase = (int*)(base + off);         off = align256(off + (size_t)(B + 1) * 4);
    int*   bcur  = (int*)(base + off);         off = align256(off + (size_t)B * BPAD * 4);
    int*   of_cnt = (int*)(base + off);        off = align256(off + 256);
    uint2* of_list = (uint2*)(base + off);
    size_t rem = (ws_size > off) ? (ws_size - off) / 8 : 0;
    int of_cap = (int)((rem < (size_t)E) ? rem : (size_t)E);

    // --- shared edge structure ---
    fill_s32_kernel<<<(B * BPAD + 255) / 256, 256, 0, stream>>>(bcur, 0, B * BPAD);
    hist_buckets_kernel<<<256, 256, 0, stream>>>(dst, bcur, B, E);
    bucket_scan_kernel<<<1, 256, 0, stream>>>(bcur, bbase, of_cnt, B, E);
    partition_kernel<<<(E + CCH - 1) / CCH, 256, 0, stream>>>(src, dst, bcur, pairs, E);
    build_ell_kernel<<<B, 256, 0, stream>>>(pairs, bbase, ell, cnt, of_list, of_cnt, N, of_cap);

    const int aggGrid = (int)(((size_t)N * 8 + 255) / 256);

    // --- conv1 (seed 0 folds relu + isolated-node fix) ---
    linear1_mfma_kernel<<<(N + 63) / 64, 256, 0, stream>>>(x, w1, b1, bufA, N);
    agg_ell_kernel<<<aggGrid, 256, 0, stream>>>(bufA, cnt, ell, bufB, N, 0.0f, 0);
    overflow_fixup_kernel<<<32, 256, 0, stream>>>(bufA, of_list, of_cnt, bufB, of_cap);

    // --- conv2 ---
    linear2_kernel<<<(N + 63) / 64, 256, 0, stream>>>(bufB, w2, b2, bufA, N);
    agg_ell_kernel<<<aggGrid, 256, 0, stream>>>(bufA, cnt, ell, out, N, -INFINITY, 1);
    overflow_fixup_kernel<<<32, 256, 0, stream>>>(bufA, of_list, of_cnt, out, of_cap);
}

// Round 11
// 268.914 us; speedup vs baseline: 4.3874x; 1.0099x over previous
//
#include <hip/hip_runtime.h>
#include <math.h>

// ---------------------------------------------------------------------------
// GCN 2-layer max-aggregation, ELL edge structure, 8-kernel pipeline:
//   fill -> hist_buckets -> bucket_scan -> partition -> build_ell ->
//   linear1_mfma -> agg1+linear2(fused, inline overflow) -> agg2(inline ovf)
//   conv1: agg1 = max(0, max h1[src]) (relu+isolated fold, seed 0);
//          h2 = agg1@w2.T+b2 computed in-block right after agg (LDS staging)
//   conv2: out = deg==0 ? 0 : max h2[src]
// Assumes N <= 131072 (B <= 256). N=100k here.
// ---------------------------------------------------------------------------

#define NPB 512       // nodes per bucket
#define BSHIFT 9
#define CAP 32        // ELL slots per node
#define CCH 2048      // edges per partition-block chunk
#define BPAD 16       // bcur padding: one counter per 64B line

typedef __attribute__((ext_vector_type(8))) short bf16x8;
typedef __attribute__((ext_vector_type(4))) float f32x4;

__global__ __launch_bounds__(256) void fill_s32_kernel(int* __restrict__ p, int v, int n) {
    int i = blockIdx.x * 256 + threadIdx.x;
    if (i < n) p[i] = v;
}

__global__ __launch_bounds__(256) void hist_buckets_kernel(
    const int* __restrict__ dst, int* __restrict__ bcnt, int B, int E)
{
    __shared__ int lc[256];
    const int tid = threadIdx.x;
    lc[tid] = 0;
    __syncthreads();
    for (int e = blockIdx.x * 256 + tid; e < E; e += gridDim.x * 256)
        atomicAdd(&lc[dst[e] >> BSHIFT], 1);
    __syncthreads();
    if (tid < B && lc[tid]) atomicAdd(&bcnt[tid * BPAD], lc[tid]);
}

__global__ __launch_bounds__(256) void bucket_scan_kernel(
    int* __restrict__ bcur, int* __restrict__ bbase, int* __restrict__ of_cnt,
    int B, int E)
{
    __shared__ int sh[256];
    const int tid = threadIdx.x;
    int v = (tid < B) ? bcur[tid * BPAD] : 0;
    sh[tid] = v;
    __syncthreads();
    #pragma unroll
    for (int d = 1; d < 256; d <<= 1) {
        int t = (tid >= d) ? sh[tid - d] : 0;
        __syncthreads();
        sh[tid] += t;
        __syncthreads();
    }
    if (tid < B) { int b = sh[tid] - v; bbase[tid] = b; bcur[tid * BPAD] = b; }
    if (tid == 0) { bbase[B] = E; *of_cnt = 0; }
}

__global__ __launch_bounds__(256) void partition_kernel(
    const int* __restrict__ src, const int* __restrict__ dst,
    int* __restrict__ bcur, uint2* __restrict__ pairs, int E)
{
    __shared__ uint2 stage[CCH];                       // 16 KB
    __shared__ int lcnt[256], loffs[256], lcur[256], gb[256], sh[256];
    const int tid = threadIdx.x;
    const int e0 = blockIdx.x * CCH;
    const int ecnt = min(CCH, E - e0);
    lcnt[tid] = 0;
    __syncthreads();
    for (int i = tid; i < ecnt; i += 256)
        atomicAdd(&lcnt[dst[e0 + i] >> BSHIFT], 1);
    __syncthreads();
    int v = lcnt[tid];
    sh[tid] = v;
    __syncthreads();
    #pragma unroll
    for (int d = 1; d < 256; d <<= 1) {
        int t = (tid >= d) ? sh[tid - d] : 0;
        __syncthreads();
        sh[tid] += t;
        __syncthreads();
    }
    loffs[tid] = sh[tid] - v;
    lcur[tid] = sh[tid] - v;
    gb[tid] = v ? atomicAdd(&bcur[tid * BPAD], v) : 0;
    __syncthreads();
    for (int i = tid; i < ecnt; i += 256) {
        int d = dst[e0 + i];
        int s = atomicAdd(&lcur[d >> BSHIFT], 1);
        stage[s] = make_uint2((unsigned)src[e0 + i], (unsigned)d);
    }
    __syncthreads();
    for (int i = tid; i < ecnt; i += 256) {
        uint2 p = stage[i];
        int b = (int)(p.y >> BSHIFT);
        pairs[gb[b] + (i - loffs[b])] = p;
    }
}

__global__ __launch_bounds__(256) void build_ell_kernel(
    const uint2* __restrict__ pairs, const int* __restrict__ bbase,
    int* __restrict__ ell, int* __restrict__ cnt,
    uint2* __restrict__ of_list, int* __restrict__ of_cnt, int N, int of_cap)
{
    __shared__ int lcnt[NPB];                          // 2 KB
    __shared__ int lell[NPB * CAP];                    // 64 KB
    const int tid = threadIdx.x, b = blockIdx.x;
    for (int i = tid; i < NPB; i += 256) lcnt[i] = 0;
    for (int i = tid; i < NPB * CAP; i += 256) lell[i] = 0;  // valid src for unused slots
    __syncthreads();
    const int p0 = bbase[b], p1 = bbase[b + 1];
    for (int i = p0 + tid; i < p1; i += 256) {
        uint2 p = pairs[i];
        int ln = (int)p.y - b * NPB;
        int s = atomicAdd(&lcnt[ln], 1);
        if (s < CAP) lell[ln * CAP + s] = (int)p.x;
        else { int oi = atomicAdd(of_cnt, 1); if (oi < of_cap) of_list[oi] = p; }
    }
    __syncthreads();
    const size_t eb = (size_t)b * NPB * CAP;
    for (int i = tid; i < NPB * CAP; i += 256) ell[eb + i] = lell[i];
    const int n0 = b * NPB;
    for (int i = tid; i < NPB; i += 256)
        if (n0 + i < N) cnt[n0 + i] = lcnt[i];
}

// Split f32 -> bf16 hi + bf16 lo (truncate; residual exact by Sterbenz).
__device__ __forceinline__ void split_bf16(float f, unsigned short& hi, unsigned short& lo) {
    unsigned u = __float_as_uint(f);
    hi = (unsigned short)(u >> 16);
    float fh = __uint_as_float(u & 0xffff0000u);
    float r = f - fh;
    lo = (unsigned short)(__float_as_uint(r) >> 16);
}

// h1 = x @ w1.T + b1 via split-bf16 MFMA (16x16x32, HW-verified frag layout).
#define L1S 136
__global__ __launch_bounds__(256) void linear1_mfma_kernel(
    const float* __restrict__ x, const float* __restrict__ w1,
    const float* __restrict__ b1, float* __restrict__ h1, int N)
{
    __shared__ unsigned short xh[64 * L1S];
    __shared__ unsigned short xl[64 * L1S];
    __shared__ unsigned short wh[32 * L1S];
    __shared__ unsigned short wl[32 * L1S];
    const int tid = threadIdx.x;
    const int node0 = blockIdx.x * 64;
    for (int q = tid; q < 32 * 32; q += 256) {
        int row = q >> 5, qc = (q & 31) * 4;
        float4 v = *reinterpret_cast<const float4*>(w1 + row * 128 + qc);
        unsigned short h0, l0, h1s, l1s, h2, l2, h3, l3;
        split_bf16(v.x, h0, l0); split_bf16(v.y, h1s, l1s);
        split_bf16(v.z, h2, l2); split_bf16(v.w, h3, l3);
        short4 hv = {(short)h0, (short)h1s, (short)h2, (short)h3};
        short4 lv = {(short)l0, (short)l1s, (short)l2, (short)l3};
        *reinterpret_cast<short4*>(&wh[row * L1S + qc]) = hv;
        *reinterpret_cast<short4*>(&wl[row * L1S + qc]) = lv;
    }
    for (int q = tid; q < 64 * 32; q += 256) {
        int row = q >> 5, qc = (q & 31) * 4;
        if (node0 + row < N) {
            float4 v = *reinterpret_cast<const float4*>(x + (size_t)(node0 + row) * 128 + qc);
            unsigned short h0, l0, h1s, l1s, h2, l2, h3, l3;
            split_bf16(v.x, h0, l0); split_bf16(v.y, h1s, l1s);
            split_bf16(v.z, h2, l2); split_bf16(v.w, h3, l3);
            short4 hv = {(short)h0, (short)h1s, (short)h2, (short)h3};
            short4 lv = {(short)l0, (short)l1s, (short)l2, (short)l3};
            *reinterpret_cast<short4*>(&xh[row * L1S + qc]) = hv;
            *reinterpret_cast<short4*>(&xl[row * L1S + qc]) = lv;
        }
    }
    __syncthreads();
    const int wid = tid >> 6, lane = tid & 63;
    const int arow = wid * 16 + (lane & 15);
    const int koff = (lane >> 4) * 8;
    bf16x8 ah[4], al[4], bh[2][4], bl[2][4];
    #pragma unroll
    for (int kt = 0; kt < 4; ++kt) {
        ah[kt] = *reinterpret_cast<const bf16x8*>(&xh[arow * L1S + kt * 32 + koff]);
        al[kt] = *reinterpret_cast<const bf16x8*>(&xl[arow * L1S + kt * 32 + koff]);
    }
    #pragma unroll
    for (int nt = 0; nt < 2; ++nt) {
        int ch = nt * 16 + (lane & 15);
        #pragma unroll
        for (int kt = 0; kt < 4; ++kt) {
            bh[nt][kt] = *reinterpret_cast<const bf16x8*>(&wh[ch * L1S + kt * 32 + koff]);
            bl[nt][kt] = *reinterpret_cast<const bf16x8*>(&wl[ch * L1S + kt * 32 + koff]);
        }
    }
    f32x4 acc[2] = {{0.f, 0.f, 0.f, 0.f}, {0.f, 0.f, 0.f, 0.f}};
    #pragma unroll
    for (int nt = 0; nt < 2; ++nt)
        #pragma unroll
        for (int kt = 0; kt < 4; ++kt) {
            acc[nt] = __builtin_amdgcn_mfma_f32_16x16x32_bf16(ah[kt], bh[nt][kt], acc[nt], 0, 0, 0);
            acc[nt] = __builtin_amdgcn_mfma_f32_16x16x32_bf16(ah[kt], bl[nt][kt], acc[nt], 0, 0, 0);
            acc[nt] = __builtin_amdgcn_mfma_f32_16x16x32_bf16(al[kt], bh[nt][kt], acc[nt], 0, 0, 0);
        }
    const int col = lane & 15, r0 = (lane >> 4) * 4;
    #pragma unroll
    for (int nt = 0; nt < 2; ++nt) {
        int ch = nt * 16 + col;
        float bias = b1[ch];
        #pragma unroll
        for (int r = 0; r < 4; ++r) {
            int n = node0 + wid * 16 + r0 + r;
            if (n < N) h1[(size_t)n * 32 + ch] = acc[nt][r] + bias;
        }
    }
}

// Shared ELL gather-max body: 8 threads/node, 4 channels each, + inline
// overflow-list scan (of_list tiny; broadcast reads, rare divergence).
__device__ __forceinline__ float4 agg_node(
    const float* __restrict__ h, const int* __restrict__ ell,
    const uint2* __restrict__ of_list, int m,
    int n, int c, int deg, float seed)
{
    const int* row = ell + (size_t)n * CAP;
    float4 acc = {seed, seed, seed, seed};
    int k = 0;
    for (; k + 1 < deg; k += 2) {
        int s0 = row[k], s1 = row[k + 1];
        float4 v0 = *reinterpret_cast<const float4*>(h + (size_t)s0 * 32 + c);
        float4 v1 = *reinterpret_cast<const float4*>(h + (size_t)s1 * 32 + c);
        acc.x = fmaxf(acc.x, fmaxf(v0.x, v1.x));
        acc.y = fmaxf(acc.y, fmaxf(v0.y, v1.y));
        acc.z = fmaxf(acc.z, fmaxf(v0.z, v1.z));
        acc.w = fmaxf(acc.w, fmaxf(v0.w, v1.w));
    }
    if (k < deg) {
        int s0 = row[k];
        float4 v0 = *reinterpret_cast<const float4*>(h + (size_t)s0 * 32 + c);
        acc.x = fmaxf(acc.x, v0.x);
        acc.y = fmaxf(acc.y, v0.y);
        acc.z = fmaxf(acc.z, v0.z);
        acc.w = fmaxf(acc.w, v0.w);
    }
    for (int e = 0; e < m; ++e) {                     // overflow (deg>CAP) edges
        uint2 p = of_list[e];
        if ((int)p.y == n) {
            float4 v0 = *reinterpret_cast<const float4*>(h + (size_t)p.x * 32 + c);
            acc.x = fmaxf(acc.x, v0.x);
            acc.y = fmaxf(acc.y, v0.y);
            acc.z = fmaxf(acc.z, v0.z);
            acc.w = fmaxf(acc.w, v0.w);
        }
    }
    return acc;
}

// conv1 agg + linear2 fused: 32 nodes/block. agg1 (seed 0 = relu+isolated
// fold) staged in LDS, then h2 = agg1@w2.T+b2 computed in-block.
__global__ __launch_bounds__(256) void agg1_lin2_kernel(
    const float* __restrict__ h1, const int* __restrict__ cnt,
    const int* __restrict__ ell, const uint2* __restrict__ of_list,
    const int* __restrict__ of_cnt, int of_cap,
    const float* __restrict__ w2, const float* __restrict__ b2,
    float* __restrict__ h2, int N)
{
    __shared__ float wsh[32][36];
    __shared__ float a1s[32][36];
    const int tid = threadIdx.x;
    for (int i = tid; i < 32 * 32; i += 256) wsh[i >> 5][i & 31] = w2[i];
    const int node0 = blockIdx.x * 32;
    const int ln = tid >> 3, c = (tid & 7) << 2;
    const int n = node0 + ln;
    const int m = min(*of_cnt, of_cap);
    float4 acc = {0.f, 0.f, 0.f, 0.f};
    if (n < N) {
        int deg = min(cnt[n], CAP);
        acc = agg_node(h1, ell, of_list, m, n, c, deg, 0.0f);
    }
    *reinterpret_cast<float4*>(&a1s[ln][c]) = acc;
    __syncthreads();
    // linear2: 8 groups x 32 lanes; group g does 4 nodes, lane j = channel j
    const int g = tid >> 5, j = tid & 31;
    const int nb = g * 4;
    const float bj = b2[j];
    float o[4] = {bj, bj, bj, bj};
    const float4* wrow = reinterpret_cast<const float4*>(&wsh[j][0]);
    #pragma unroll
    for (int k4 = 0; k4 < 8; ++k4) {
        float4 w = wrow[k4];
        #pragma unroll
        for (int a = 0; a < 4; ++a) {
            float4 xv = *reinterpret_cast<const float4*>(&a1s[nb + a][k4 * 4]);
            o[a] += xv.x * w.x + xv.y * w.y + xv.z * w.z + xv.w * w.w;
        }
    }
    #pragma unroll
    for (int a = 0; a < 4; ++a) {
        int nn = node0 + nb + a;
        if (nn < N) h2[(size_t)nn * 32 + j] = o[a];
    }
}

// conv2 agg: seed=-inf, deg==0 -> 0, inline overflow, writes d_out.
__global__ __launch_bounds__(256) void agg2_kernel(
    const float* __restrict__ h2, const int* __restrict__ cnt,
    const int* __restrict__ ell, const uint2* __restrict__ of_list,
    const int* __restrict__ of_cnt, int of_cap,
    float* __restrict__ out, int N)
{
    int t = blockIdx.x * 256 + threadIdx.x;
    int n = t >> 3;
    if (n >= N) return;
    int c = (t & 7) << 2;
    const int m = min(*of_cnt, of_cap);
    int total = cnt[n];
    int deg = min(total, CAP);
    float4 acc = agg_node(h2, ell, of_list, m, n, c, deg, -INFINITY);
    if (total == 0) acc = make_float4(0.f, 0.f, 0.f, 0.f);
    *reinterpret_cast<float4*>(out + (size_t)n * 32 + c) = acc;
}

extern "C" void kernel_launch(void* const* d_in, const int* in_sizes, int n_in,
                              void* d_out, int out_size, void* d_ws, size_t ws_size,
                              hipStream_t stream)
{
    const float* x  = (const float*)d_in[0];
    const int*   ei = (const int*)d_in[1];
    const float* w1 = (const float*)d_in[2];
    const float* b1 = (const float*)d_in[3];
    const float* w2 = (const float*)d_in[4];
    const float* b2 = (const float*)d_in[5];
    float* out = (float*)d_out;

    const int N = in_sizes[0] / 128;
    const int E = in_sizes[1] / 2;
    const int C = (int)((size_t)N * 32);
    const int B = (N + NPB - 1) / NPB;          // <=256 for N<=131072
    const int* src = ei;
    const int* dst = ei + E;

    auto align256 = [](size_t v) { return (v + 255) & ~(size_t)255; };
    size_t off = 0;
    // Region R: pairs (E*8 B) until build_ell, then bufA = h1/h2 (C*4 B).
    size_t rsize = (size_t)C * 4 > (size_t)E * 8 ? (size_t)C * 4 : (size_t)E * 8;
    char* base = (char*)d_ws;
    uint2* pairs = (uint2*)(base + off);
    float* bufA  = (float*)(base + off);       off = align256(off + rsize);   // h1
    float* bufB  = (float*)(base + off);       off = align256(off + (size_t)C * 4);  // h2
    int*   ell   = (int*)(base + off);         off = align256(off + (size_t)B * NPB * CAP * 4);
    int*   cnt   = (int*)(base + off);         off = align256(off + (size_t)N * 4);
    int*   bbase = (int*)(base + off);         off = align256(off + (size_t)(B + 1) * 4);
    int*   bcur  = (int*)(base + off);         off = align256(off + (size_t)B * BPAD * 4);
    int*   of_cnt = (int*)(base + off);        off = align256(off + 256);
    uint2* of_list = (uint2*)(base + off);
    size_t rem = (ws_size > off) ? (ws_size - off) / 8 : 0;
    int of_cap = (int)((rem < (size_t)E) ? rem : (size_t)E);

    // --- shared edge structure ---
    fill_s32_kernel<<<(B * BPAD + 255) / 256, 256, 0, stream>>>(bcur, 0, B * BPAD);
    hist_buckets_kernel<<<256, 256, 0, stream>>>(dst, bcur, B, E);
    bucket_scan_kernel<<<1, 256, 0, stream>>>(bcur, bbase, of_cnt, B, E);
    partition_kernel<<<(E + CCH - 1) / CCH, 256, 0, stream>>>(src, dst, bcur, pairs, E);
    build_ell_kernel<<<B, 256, 0, stream>>>(pairs, bbase, ell, cnt, of_list, of_cnt, N, of_cap);

    const int nodeGrid = (N + 31) / 32;

    // --- conv1 + linear2 (fused) ---
    linear1_mfma_kernel<<<(N + 63) / 64, 256, 0, stream>>>(x, w1, b1, bufA, N);
    agg1_lin2_kernel<<<nodeGrid, 256, 0, stream>>>(
        bufA, cnt, ell, of_list, of_cnt, of_cap, w2, b2, bufB, N);

    // --- conv2 ---
    agg2_kernel<<<nodeGrid, 256, 0, stream>>>(
        bufB, cnt, ell, of_list, of_cnt, of_cap, out, N);
}